// Round 7
// baseline (445.612 us; speedup 1.0000x reference)
//
#include <hip/hip_runtime.h>

typedef float f32x4 __attribute__((ext_vector_type(4)));

// Problem shape (fixed by setup_inputs): B=64, C=1024, H*W=1024, M=768.
#define NB 64
#define NC 1024
#define HW 1024
#define HW4 256          // HW / 4
#define CCH 16           // channel groups; grid = CCH*NB = 1024 blocks
#define CPC (NC / CCH)   // 64 channels per group
#define FPAD 32          // flag padding (128 B) to avoid line contention

// Zero the sync counters (must run every call: graph replays reuse d_ws).
__global__ void adl_init_flags(int* __restrict__ flags) {
    flags[threadIdx.x * FPAD] = 0;          // 128 threads: cnt[64] + cnt2[64]
}

// Fused ADL, non-cooperative. Block bid -> (cg = bid>>6, b = bid&63).
// Phase 1: GEMV partial[cg][b][hw] = sum_{c in chunk} fm[b,c,hw]*w[c];
//          bump cnt[b] (release, agent scope).
// Phase 2: blocks cg<4 spin until cnt[b]==16, reduce partials -> logits in
//          LDS, write attn (sigmoid), rank element tt=cg*256+t over the full
//          row (value desc, index asc — matches lax.top_k; ranking on the
//          logit, sigmoid strictly monotone), write mask slice, bump cnt2[b].
// Phase 3: all blocks spin until cnt2[b]==4, load mask row, out = fm*mask.
//          fm re-read hits L3 (proven by round-5 FETCH=260MB); NT load/store.
__global__ void __launch_bounds__(256, 4)
adl_fused_spin(const float* __restrict__ fm,
               const float* __restrict__ w,
               const float* __restrict__ conv_b,
               const int* __restrict__ Mptr,
               float* __restrict__ out,
               float* __restrict__ attn_out,
               float* __restrict__ partial,
               float* __restrict__ mask,
               int* __restrict__ cnt,
               int* __restrict__ cnt2) {
    const int bid = blockIdx.x;
    const int b   = bid & (NB - 1);
    const int cg  = bid >> 6;
    const int t   = threadIdx.x;             // 0..255

    __shared__ float wsh[CPC];
    __shared__ f32x4 s_sh4[HW4];
    float* s_sh = (float*)s_sh4;

    // ---- phase 1: GEMV chunk ----
    if (t < CPC) wsh[t] = w[cg * CPC + t];
    __syncthreads();
    const f32x4* fm4 = (const f32x4*)fm;
    {
        size_t base = ((size_t)(b * NC + cg * CPC)) * HW4 + t;
        f32x4 acc = {0.f, 0.f, 0.f, 0.f};
        #pragma unroll 8
        for (int ci = 0; ci < CPC; ++ci) {
            acc += fm4[base] * wsh[ci];
            base += HW4;
        }
        ((f32x4*)partial)[((size_t)(cg * NB + b)) * HW4 + t] = acc;
    }
    __threadfence();
    __syncthreads();
    if (t == 0)
        __hip_atomic_fetch_add(&cnt[b * FPAD], 1, __ATOMIC_RELEASE,
                               __HIP_MEMORY_SCOPE_AGENT);

    // ---- phase 2: rank blocks only (cg < 4) ----
    if (cg < 4) {
        if (t == 0) {
            while (__hip_atomic_load(&cnt[b * FPAD], __ATOMIC_ACQUIRE,
                                     __HIP_MEMORY_SCOPE_AGENT) < CCH)
                __builtin_amdgcn_s_sleep(4);
        }
        __syncthreads();
        const float bias = conv_b[0];
        #pragma unroll
        for (int q = 0; q < 4; ++q) {
            const int tt = q * 256 + t;
            float s = bias;
            #pragma unroll
            for (int k = 0; k < CCH; ++k)
                s += partial[((size_t)(k * NB + b)) * HW + tt];
            s_sh[tt] = s;
        }
        __syncthreads();
        const int tt = cg * 256 + t;         // this thread's element
        const float sv = s_sh[tt];
        const int M = *Mptr;
        attn_out[(size_t)b * HW + tt] = 1.0f / (1.0f + expf(-sv));
        int r = 0;
        #pragma unroll 4
        for (int j4 = 0; j4 < HW4; ++j4) {
            const f32x4 v = s_sh4[j4];       // broadcast LDS read
            const int j = j4 * 4;
            r += (v.x > sv) || (v.x == sv && (j + 0) < tt);
            r += (v.y > sv) || (v.y == sv && (j + 1) < tt);
            r += (v.z > sv) || (v.z == sv && (j + 2) < tt);
            r += (v.w > sv) || (v.w == sv && (j + 3) < tt);
        }
        mask[(size_t)b * HW + tt] = (r < M) ? 0.0f : 1.0f;
        __threadfence();
        __syncthreads();
        if (t == 0)
            __hip_atomic_fetch_add(&cnt2[b * FPAD], 1, __ATOMIC_RELEASE,
                                   __HIP_MEMORY_SCOPE_AGENT);
    }

    // ---- phase 3: apply (all blocks) ----
    if (t == 0) {
        while (__hip_atomic_load(&cnt2[b * FPAD], __ATOMIC_ACQUIRE,
                                 __HIP_MEMORY_SCOPE_AGENT) < 4)
            __builtin_amdgcn_s_sleep(4);
    }
    __syncthreads();
    {
        const f32x4* mask4 = (const f32x4*)mask;
        f32x4* out4        = (f32x4*)out;
        const f32x4 m = mask4[b * HW4 + t];  // loop-invariant per thread
        size_t base = ((size_t)(b * NC + cg * CPC)) * HW4 + t;
        #pragma unroll 4
        for (int ci = 0; ci < CPC; ++ci) {
            const f32x4 v = __builtin_nontemporal_load(&fm4[base]);
            __builtin_nontemporal_store(v * m, &out4[base]);
            base += HW4;
        }
    }
}

extern "C" void kernel_launch(void* const* d_in, const int* in_sizes, int n_in,
                              void* d_out, int out_size, void* d_ws, size_t ws_size,
                              hipStream_t stream) {
    const float* fm   = (const float*)d_in[0];   // [64,1024,32,32] f32
    const float* w    = (const float*)d_in[1];   // [1024] f32
    const float* bias = (const float*)d_in[2];   // [1] f32
    const int*   Mptr = (const int*)d_in[3];     // scalar int (768)

    float* out      = (float*)d_out;                       // dropped [B,C,H,W]
    float* attn_out = out + (size_t)NB * NC * HW;          // attn [B,1,H,W]

    // Workspace: partial [CCH][NB][HW] f32 (4 MB) + mask [NB][HW] f32 (256 KB)
    // + padded flags cnt[64*FPAD], cnt2[64*FPAD] (16 KB).
    float* partial = (float*)d_ws;
    float* mask    = partial + (size_t)CCH * NB * HW;
    int*   cnt     = (int*)(mask + (size_t)NB * HW);
    int*   cnt2    = cnt + NB * FPAD;

    adl_init_flags<<<1, 2 * NB, 0, stream>>>(cnt);
    adl_fused_spin<<<CCH * NB, 256, 0, stream>>>(fm, w, bias, Mptr, out,
                                                 attn_out, partial, mask,
                                                 cnt, cnt2);
}

// Round 8
// 162.289 us; speedup vs baseline: 2.7458x; 2.7458x over previous
//
#include <hip/hip_runtime.h>

typedef float f32x4 __attribute__((ext_vector_type(4)));

// Problem shape (fixed by setup_inputs): B=64, C=1024, H*W=1024, M=768.
#define NB 64
#define NC 1024
#define HW 1024
#define HW4 256          // HW / 4
#define CCH 16           // channel splits in the GEMV
#define CPC (NC / CCH)   // 64 channels per split
#define CGRP 16          // channel groups in apply
#define CPG (NC / CGRP)  // 64 channels per group

// Kernel A: split-K GEMV, stream-structured. Block (cg, b); thread t owns
// hw4 = t for the whole block, so the inner loop over CPC channels is just
// base += HW4 (4 KB row stride), load f32x4, fma. Fully coalesced.
// Regular loads: fills L3 with fm for the apply pass (and stays resident
// across graph replays — only ~4.5 MB of scratch ever evicts).
__global__ void __launch_bounds__(256)
adl_gemv(const float* __restrict__ fm,
         const float* __restrict__ w,
         float* __restrict__ partial) {
    const int cg = blockIdx.x;               // 0..CCH-1
    const int b  = blockIdx.y;               // 0..NB-1
    const int t  = threadIdx.x;              // 0..255 == hw4
    const f32x4* fm4 = (const f32x4*)fm;
    const int cbase = cg * CPC;
    size_t base = ((size_t)(b * NC + cbase)) * HW4 + t;
    f32x4 acc = {0.f, 0.f, 0.f, 0.f};
    #pragma unroll 8
    for (int ci = 0; ci < CPC; ++ci) {
        acc += fm4[base] * w[cbase + ci];    // w: wave-uniform s_load
        base += HW4;
    }
    ((f32x4*)partial)[((size_t)(cg * NB + b)) * HW4 + t] = acc;
}

// Kernel B: reduce partials -> logit, sigmoid -> attn output, exact top-M
// drop mask via per-element descending rank with index tie-break (matches
// lax.top_k). Rank on the LOGIT (sigmoid strictly monotone). Grid (4, NB).
__global__ void __launch_bounds__(256)
adl_topk_mask(const float* __restrict__ partial,
              const float* __restrict__ conv_b,
              const int* __restrict__ Mptr,
              float* __restrict__ attn_out,
              float* __restrict__ mask) {
    __shared__ f32x4 s_sh4[HW4];
    float* s_sh = (float*)s_sh4;
    const int slice = blockIdx.x;            // 0..3
    const int b     = blockIdx.y;            // 0..NB-1
    const int tid   = threadIdx.x;           // 0..255
    const float bias = conv_b[0];
    #pragma unroll
    for (int q = 0; q < 4; ++q) {
        const int t = q * 256 + tid;
        float s = bias;
        #pragma unroll 8
        for (int k = 0; k < CCH; ++k)
            s += partial[((size_t)(k * NB + b)) * HW + t];
        s_sh[t] = s;
    }
    __syncthreads();
    const int t = slice * 256 + tid;         // this thread's element
    const float sv = s_sh[t];
    const int M = *Mptr;
    int r = 0;
    #pragma unroll 4
    for (int j4 = 0; j4 < HW4; ++j4) {
        const f32x4 v = s_sh4[j4];           // broadcast LDS read
        const int j = j4 * 4;
        r += (v.x > sv) || (v.x == sv && (j + 0) < t);
        r += (v.y > sv) || (v.y == sv && (j + 1) < t);
        r += (v.z > sv) || (v.z == sv && (j + 2) < t);
        r += (v.w > sv) || (v.w == sv && (j + 3) < t);
    }
    attn_out[(size_t)b * HW + t] = 1.0f / (1.0f + expf(-sv));
    mask[(size_t)b * HW + t] = (r < M) ? 0.0f : 1.0f;
}

// Kernel C: out = fm * mask, stream-structured. Block (cg, b); thread t owns
// hw4 = t, so the mask element is LOOP-INVARIANT (one 16 B load per thread).
// fm via REGULAR loads (round-7 change: nt loads may bypass L3 even on hit;
// fm is L3-resident from the GEMV). NT stores: out never pollutes caches.
__global__ void __launch_bounds__(256)
adl_apply(const float* __restrict__ fm,
          const float* __restrict__ mask,
          float* __restrict__ out) {
    const int cg = blockIdx.x;               // 0..CGRP-1
    const int b  = blockIdx.y;               // 0..NB-1
    const int t  = threadIdx.x;              // 0..255 == hw4
    const f32x4* fm4   = (const f32x4*)fm;
    const f32x4* mask4 = (const f32x4*)mask;
    f32x4* out4        = (f32x4*)out;
    const f32x4 m = mask4[b * HW4 + t];
    size_t base = ((size_t)(b * NC + cg * CPG)) * HW4 + t;
    #pragma unroll 8
    for (int ci = 0; ci < CPG; ++ci) {
        const f32x4 v = fm4[base];
        __builtin_nontemporal_store(v * m, &out4[base]);
        base += HW4;
    }
}

extern "C" void kernel_launch(void* const* d_in, const int* in_sizes, int n_in,
                              void* d_out, int out_size, void* d_ws, size_t ws_size,
                              hipStream_t stream) {
    const float* fm   = (const float*)d_in[0];   // [64,1024,32,32] f32
    const float* w    = (const float*)d_in[1];   // [1024] f32
    const float* bias = (const float*)d_in[2];   // [1] f32
    const int*   Mptr = (const int*)d_in[3];     // scalar int (768)

    float* out      = (float*)d_out;                       // dropped [B,C,H,W]
    float* attn_out = out + (size_t)NB * NC * HW;          // attn [B,1,H,W]

    // Workspace: partial [CCH][NB][HW] f32 (4 MB) + mask [NB][HW] f32 (256 KB).
    float* partial = (float*)d_ws;
    float* mask    = partial + (size_t)CCH * NB * HW;

    adl_gemv<<<dim3(CCH, NB), 256, 0, stream>>>(fm, w, partial);
    adl_topk_mask<<<dim3(4, NB), 256, 0, stream>>>(partial, bias, Mptr, attn_out, mask);
    adl_apply<<<dim3(CGRP, NB), 256, 0, stream>>>(fm, mask, out);
}

// Round 9
// 160.873 us; speedup vs baseline: 2.7700x; 1.0088x over previous
//
#include <hip/hip_runtime.h>

typedef float f32x4 __attribute__((ext_vector_type(4)));

// Problem shape (fixed by setup_inputs): B=64, C=1024, H*W=1024, M=768.
#define NB 64
#define NC 1024
#define HW 1024
#define HW4 256          // HW / 4
#define CCH 16           // channel splits in the GEMV
#define CPC (NC / CCH)   // 64 channels per split
#define CGRP 16          // channel groups in apply
#define CPG (NC / CGRP)  // 64 channels per group

// Kernel A: split-K GEMV, stream-structured. Block (cg, b); thread t owns
// hw4 = t for the whole block; inner loop over CPC channels is base += HW4
// (4 KB row stride), load f32x4, fma. Fully coalesced 1 KB/wave/instr.
__global__ void __launch_bounds__(256)
adl_gemv(const float* __restrict__ fm,
         const float* __restrict__ w,
         float* __restrict__ partial) {
    const int cg = blockIdx.x;               // 0..CCH-1
    const int b  = blockIdx.y;               // 0..NB-1
    const int t  = threadIdx.x;              // 0..255 == hw4
    const f32x4* fm4 = (const f32x4*)fm;
    const int cbase = cg * CPC;
    size_t base = ((size_t)(b * NC + cbase)) * HW4 + t;
    f32x4 acc = {0.f, 0.f, 0.f, 0.f};
    #pragma unroll 8
    for (int ci = 0; ci < CPC; ++ci) {
        acc += fm4[base] * w[cbase + ci];    // w: wave-uniform s_load
        base += HW4;
    }
    ((f32x4*)partial)[((size_t)(cg * NB + b)) * HW4 + t] = acc;
}

// Kernel B: reduce partials -> logit, sigmoid -> attn output, exact top-M
// drop mask via per-element descending rank with index tie-break (matches
// lax.top_k). Rank on the LOGIT (sigmoid strictly monotone). Grid (4, NB).
__global__ void __launch_bounds__(256)
adl_topk_mask(const float* __restrict__ partial,
              const float* __restrict__ conv_b,
              const int* __restrict__ Mptr,
              float* __restrict__ attn_out,
              float* __restrict__ mask) {
    __shared__ f32x4 s_sh4[HW4];
    float* s_sh = (float*)s_sh4;
    const int slice = blockIdx.x;            // 0..3
    const int b     = blockIdx.y;            // 0..NB-1
    const int tid   = threadIdx.x;           // 0..255
    const float bias = conv_b[0];
    #pragma unroll
    for (int q = 0; q < 4; ++q) {
        const int t = q * 256 + tid;
        float s = bias;
        #pragma unroll 8
        for (int k = 0; k < CCH; ++k)
            s += partial[((size_t)(k * NB + b)) * HW + t];
        s_sh[t] = s;
    }
    __syncthreads();
    const int t = slice * 256 + tid;         // this thread's element
    const float sv = s_sh[t];
    const int M = *Mptr;
    int r = 0;
    #pragma unroll 4
    for (int j4 = 0; j4 < HW4; ++j4) {
        const f32x4 v = s_sh4[j4];           // broadcast LDS read
        const int j = j4 * 4;
        r += (v.x > sv) || (v.x == sv && (j + 0) < t);
        r += (v.y > sv) || (v.y == sv && (j + 1) < t);
        r += (v.z > sv) || (v.z == sv && (j + 2) < t);
        r += (v.w > sv) || (v.w == sv && (j + 3) < t);
    }
    attn_out[(size_t)b * HW + t] = 1.0f / (1.0f + expf(-sv));
    mask[(size_t)b * HW + t] = (r < M) ? 0.0f : 1.0f;
}

// Kernel C: out = fm * mask, stream-structured. Block (cg, b); thread t owns
// hw4 = t (mask element loop-invariant). ROUND-9 CHANGE: explicit 8-wide
// batching — 8 independent loads issued back-to-back, then 8 NT stores —
// to give the DRAM controller long same-direction bursts instead of
// per-element read/write turnaround. Full unroll keeps v[] in registers.
__global__ void __launch_bounds__(256)
adl_apply(const float* __restrict__ fm,
          const float* __restrict__ mask,
          float* __restrict__ out) {
    const int cg = blockIdx.x;               // 0..CGRP-1
    const int b  = blockIdx.y;               // 0..NB-1
    const int t  = threadIdx.x;              // 0..255 == hw4
    const f32x4* fm4   = (const f32x4*)fm;
    const f32x4* mask4 = (const f32x4*)mask;
    f32x4* out4        = (f32x4*)out;
    const f32x4 m = mask4[b * HW4 + t];
    size_t base = ((size_t)(b * NC + cg * CPG)) * HW4 + t;
    #pragma unroll 1
    for (int g = 0; g < CPG / 8; ++g) {      // 8 groups of 8 channels
        f32x4 v[8];
        #pragma unroll
        for (int k = 0; k < 8; ++k)
            v[k] = fm4[base + (size_t)k * HW4];
        #pragma unroll
        for (int k = 0; k < 8; ++k)
            __builtin_nontemporal_store(v[k] * m, &out4[base + (size_t)k * HW4]);
        base += (size_t)8 * HW4;
    }
}

extern "C" void kernel_launch(void* const* d_in, const int* in_sizes, int n_in,
                              void* d_out, int out_size, void* d_ws, size_t ws_size,
                              hipStream_t stream) {
    const float* fm   = (const float*)d_in[0];   // [64,1024,32,32] f32
    const float* w    = (const float*)d_in[1];   // [1024] f32
    const float* bias = (const float*)d_in[2];   // [1] f32
    const int*   Mptr = (const int*)d_in[3];     // scalar int (768)

    float* out      = (float*)d_out;                       // dropped [B,C,H,W]
    float* attn_out = out + (size_t)NB * NC * HW;          // attn [B,1,H,W]

    // Workspace: partial [CCH][NB][HW] f32 (4 MB) + mask [NB][HW] f32 (256 KB).
    float* partial = (float*)d_ws;
    float* mask    = partial + (size_t)CCH * NB * HW;

    adl_gemv<<<dim3(CCH, NB), 256, 0, stream>>>(fm, w, partial);
    adl_topk_mask<<<dim3(4, NB), 256, 0, stream>>>(partial, bias, Mptr, attn_out, mask);
    adl_apply<<<dim3(CGRP, NB), 256, 0, stream>>>(fm, mask, out);
}